// Round 14
// baseline (38.280 us; speedup 1.0000x reference)
//
#include <hip/hip_runtime.h>

#ifndef __has_builtin
#define __has_builtin(x) 0
#endif

__device__ __forceinline__ float fexp2(float x) {
#if __has_builtin(__builtin_amdgcn_exp2f)
    return __builtin_amdgcn_exp2f(x);
#else
    return exp2f(x);
#endif
}
__device__ __forceinline__ float frcp(float x) {
#if __has_builtin(__builtin_amdgcn_rcpf)
    return __builtin_amdgcn_rcpf(x);
#else
    return 1.0f / x;
#endif
}

constexpr int TT = 32;    // directions T
constexpr int SS = 32;    // steps S
constexpr int BB = 64;    // graphs B
constexpr int NB = 64;    // partition blocks for edge sort
constexpr int CPB_N = 8;  // chunks per graph, node part  -> 512 node tiles
constexpr int CPB_E = 16; // chunks per graph, edge part  -> 1024 edge tiles
constexpr int CELLS = SS * TT;  // 1024 cells per tile
constexpr float FL = 50.0f * 1.44269504088896340736f;  // steepness * log2(e)
constexpr float QS = 65536.0f;                          // fixed-point scale 2^16
constexpr float IQS = 1.0f / 65536.0f;

// ---- prep: bounds + edge hist (also emits ge[e] = graph of edge) ----
__global__ __launch_bounds__(256) void prep_k(
    const int* __restrict__ batch, const int* __restrict__ src,
    int N, int E, int nB,
    int* __restrict__ starts, int* __restrict__ hist, int* __restrict__ ge)
{
    if ((int)blockIdx.x < nB) {
        const int n = blockIdx.x * 256 + threadIdx.x;
        if (n >= N) return;
        const int g = batch[n];
        const int gp = (n == 0) ? -1 : batch[n - 1];
        for (int g2 = gp + 1; g2 <= g; ++g2) starts[g2] = n;
        if (n == N - 1)
            for (int g2 = g + 1; g2 <= BB; ++g2) starts[g2] = N;
    } else {
        const int b = blockIdx.x - nB;      // 0..NB-1
        __shared__ int h[BB];
        if (threadIdx.x < BB) h[threadIdx.x] = 0;
        __syncthreads();
        const int per = (E + NB - 1) / NB;
        const int lo = b * per, hi = min(E, lo + per);
        for (int e = lo + threadIdx.x; e < hi; e += 256) {
            const int g = batch[src[e]];
            ge[e] = g;
            atomicAdd(&h[g], 1);
        }
        __syncthreads();
        if (threadIdx.x < BB) hist[b * BB + threadIdx.x] = h[threadIdx.x];
    }
}

// ---- ECT core: window-3 sigmoid + histogram suffix, u32 fixed-point LDS atomics ----
// Epilogue writes the block's 1024-cell partial tile with PLAIN coalesced stores
// (no device-scope atomics); reduce_k sums tiles per graph afterwards.
__device__ __forceinline__ void ect_core(
    const float* __restrict__ x, const float* __restrict__ v,
    const float* __restrict__ lin, const int2* __restrict__ epair,
    bool edge, int lo, int hi, float* __restrict__ pbt)
{
    __shared__ unsigned accS[TT][SS + 1];
    __shared__ unsigned cntS[TT][SS + 1];
    __shared__ unsigned part[TT][9];
    for (int i = threadIdx.x; i < TT * (SS + 1); i += 256) {
        ((unsigned*)accS)[i] = 0u;
        ((unsigned*)cntS)[i] = 0u;
    }
    const int t = threadIdx.x & 31;
    const int pr = threadIdx.x >> 5;
    const float v0 = v[t], v1 = v[TT + t], v2 = v[2 * TT + t];
    const float l0 = lin[0];
    const float dS = lin[1] - l0;
    const float invD = frcp(dS);
    const float fld = FL * dS;                 // ~5.12 exp2-units per bin
    const float pm1 = fexp2(fld), pp1 = fexp2(-fld);
    __syncthreads();

    for (int p = lo + pr; p < hi; p += 8) {
        float h;
        if (edge) {
            const int2 ed = epair[p];
            const float hs = fmaf(x[3 * ed.x], v0, fmaf(x[3 * ed.x + 1], v1, x[3 * ed.x + 2] * v2));
            const float hd = fmaf(x[3 * ed.y], v0, fmaf(x[3 * ed.y + 1], v1, x[3 * ed.y + 2] * v2));
            h = fmaxf(hs, hd);
        } else {
            h = fmaf(x[3 * p], v0, fmaf(x[3 * p + 1], v1, x[3 * p + 2] * v2));
        }
        const float hl0 = h - l0;
        float fj = rintf(hl0 * invD);
        fj = fminf(34.f, fmaxf(-2.f, fj));
        const int j = (int)fj;
        const float delta = fmaf(-fj, dS, hl0);   // h - l_j
        const float ucen = fexp2(FL * delta);     // in [0.17, 5.9] when unclamped
        const unsigned q0 = __float2uint_rn(QS * frcp(fmaf(ucen, pm1, 1.f))); // s=j-1
        const unsigned q1 = __float2uint_rn(QS * frcp(1.f + ucen));           // s=j
        const unsigned q2 = __float2uint_rn(QS * frcp(fmaf(ucen, pp1, 1.f))); // s=j+1
        const int b = j + 2;
        if (b < SS) atomicAdd(&cntS[t][b], 1u);
        if (1 <= j && j <= SS) atomicAdd(&accS[t][j - 1], q0);
        if (0 <= j && j < SS)  atomicAdd(&accS[t][j], q1);
        if (-1 <= j && j < SS - 1) atomicAdd(&accS[t][j + 1], q2);
    }
    __syncthreads();
    // two-level scan: thread (t, q=pr) owns s in [4q, 4q+4)
    const unsigned c0 = cntS[t][4 * pr], c1 = cntS[t][4 * pr + 1];
    const unsigned c2 = cntS[t][4 * pr + 2], c3 = cntS[t][4 * pr + 3];
    part[t][pr + 1] = c0 + c1 + c2 + c3;
    if (pr == 0) part[t][0] = 0u;
    __syncthreads();
    if (pr == 0) {
        unsigned r = 0u;
#pragma unroll
        for (int q = 1; q <= 8; ++q) { r += part[t][q]; part[t][q] = r; }
    }
    __syncthreads();
    unsigned run = part[t][pr];
    run += c0;
    pbt[(4 * pr + 0) * TT + t] = fmaf((float)accS[t][4 * pr + 0], IQS, (float)run);
    run += c1;
    pbt[(4 * pr + 1) * TT + t] = fmaf((float)accS[t][4 * pr + 1], IQS, (float)run);
    run += c2;
    pbt[(4 * pr + 2) * TT + t] = fmaf((float)accS[t][4 * pr + 2], IQS, (float)run);
    run += c3;
    pbt[(4 * pr + 3) * TT + t] = fmaf((float)accS[t][4 * pr + 3], IQS, (float)run);
}

// ---- k2: scatter blocks (0..NB-1) ∥ node-ect blocks (tiles 0..511) ----
__global__ __launch_bounds__(256) void mid_k(
    const float* __restrict__ x, const float* __restrict__ v,
    const float* __restrict__ lin,
    const int* __restrict__ src, const int* __restrict__ dst,
    const int* __restrict__ ge, int E,
    const int* __restrict__ hist, int* __restrict__ offs,
    int2* __restrict__ epair,
    const int* __restrict__ starts, float* __restrict__ pb)
{
    if ((int)blockIdx.x < NB) {
        __shared__ int lcur[BB];
        __shared__ int stot[BB];
        const int tid = threadIdx.x;
        if (tid < BB) {
            int accb = 0, tot = 0;
            for (int b = 0; b < NB; ++b) {
                const int hv = hist[b * BB + tid];
                accb += (b < (int)blockIdx.x) ? hv : 0;
                tot += hv;
            }
            lcur[tid] = accb;
            stot[tid] = tot;
        }
        __syncthreads();
        if (tid == 0) {
            int run = 0;
            for (int i = 0; i < BB; ++i) { const int tv = stot[i]; stot[i] = run; run += tv; }
            if (blockIdx.x == 0) offs[BB] = run;
        }
        __syncthreads();
        if (tid < BB) {
            lcur[tid] += stot[tid];
            if (blockIdx.x == 0) offs[tid] = stot[tid];
        }
        __syncthreads();
        const int per = (E + NB - 1) / NB;
        const int lo = blockIdx.x * per, hi = min(E, lo + per);
        for (int e = lo + tid; e < hi; e += 256) {
            const int pos = atomicAdd(&lcur[ge[e]], 1);
            epair[pos] = int2{src[e], dst[e]};
        }
    } else {
        const int bid = blockIdx.x - NB;               // node tile id 0..511
        const int g = bid / CPB_N, c = bid % CPB_N;
        const int s0 = starts[g], s1 = starts[g + 1];
        const int chunk = (s1 - s0 + CPB_N - 1) / CPB_N;
        const int lo = s0 + c * chunk;
        const int hi = min(s1, lo + chunk);
        ect_core(x, v, lin, nullptr, false, lo, hi, pb + (size_t)bid * CELLS);
    }
}

// ---- k3: edge-ect (tiles 512..1535) ----
__global__ __launch_bounds__(256) void edge_k(
    const float* __restrict__ x, const float* __restrict__ v,
    const float* __restrict__ lin, const int2* __restrict__ epair,
    const int* __restrict__ offs, float* __restrict__ pb)
{
    const int g = blockIdx.x / CPB_E, c = blockIdx.x % CPB_E;
    const int s0 = offs[g], s1 = offs[g + 1];
    const int chunk = (s1 - s0 + CPB_E - 1) / CPB_E;
    const int lo = s0 + c * chunk;
    const int hi = min(s1, lo + chunk);
    ect_core(x, v, lin, epair, true, lo, hi,
             pb + (size_t)(BB * CPB_N + blockIdx.x) * CELLS);
}

// ---- k4: reduce partial tiles -> out (no atomics anywhere) ----
__global__ __launch_bounds__(256) void reduce_k(
    const float* __restrict__ pb, float* __restrict__ out)
{
    const int g = blockIdx.x;          // 0..BB-1
    const int tid = threadIdx.x;
    float a0 = 0.f, a1 = 0.f, a2 = 0.f, a3 = 0.f;
    const float* pn = pb + (size_t)g * CPB_N * CELLS;
#pragma unroll
    for (int s = 0; s < CPB_N; ++s) {
        const float* p = pn + s * CELLS;
        a0 += p[tid]; a1 += p[256 + tid]; a2 += p[512 + tid]; a3 += p[768 + tid];
    }
    const float* pe = pb + (size_t)(BB * CPB_N + g * CPB_E) * CELLS;
#pragma unroll
    for (int s = 0; s < CPB_E; ++s) {
        const float* p = pe + s * CELLS;
        a0 -= p[tid]; a1 -= p[256 + tid]; a2 -= p[512 + tid]; a3 -= p[768 + tid];
    }
    float* o = out + (size_t)g * CELLS;
    o[tid] = a0; o[256 + tid] = a1; o[512 + tid] = a2; o[768 + tid] = a3;
}

extern "C" void kernel_launch(void* const* d_in, const int* in_sizes, int n_in,
                              void* d_out, int out_size, void* d_ws, size_t ws_size,
                              hipStream_t stream) {
    const float* x   = (const float*)d_in[0];
    const float* v   = (const float*)d_in[1];
    const float* lin = (const float*)d_in[2];
    const int* edge_index = (const int*)d_in[3];
    const int* batch = (const int*)d_in[4];

    const int N = in_sizes[0] / 3;
    const int E = in_sizes[3] / 2;
    const int* src = edge_index;       // edge_index[0][:]
    const int* dst = edge_index + E;   // edge_index[1][:]
    float* out = (float*)d_out;

    char* ws = (char*)d_ws;
    int* starts = (int*)ws;                                   // 65 ints
    int* offs   = (int*)(ws + 512);                           // 65 ints
    int* hist   = (int*)(ws + 1024);                          // NB*BB ints (16 KB)
    float* pb   = (float*)(ws + 32768);                       // 1536*1024 f32 (6 MB)
    char* after_pb = ws + 32768 + (size_t)(BB * (CPB_N + CPB_E)) * CELLS * 4;
    int* ge     = (int*)after_pb;                             // E ints
    int2* epair = (int2*)(after_pb + (((size_t)E * 4 + 255) / 256) * 256);  // E int2

    const int nB = (N + 255) / 256;
    prep_k<<<nB + NB, 256, 0, stream>>>(batch, src, N, E, nB, starts, hist, ge);
    mid_k<<<NB + BB * CPB_N, 256, 0, stream>>>(x, v, lin, src, dst, ge, E,
                                               hist, offs, epair, starts, pb);
    edge_k<<<BB * CPB_E, 256, 0, stream>>>(x, v, lin, epair, offs, pb);
    reduce_k<<<BB, 256, 0, stream>>>(pb, out);
}